// Round 7
// baseline (248.021 us; speedup 1.0000x reference)
//
#include <hip/hip_runtime.h>

#define N_ITER 100

typedef float f2 __attribute__((ext_vector_type(2)));

// Guaranteed-packed fp32 pair math (VOP3P).
__device__ __forceinline__ f2 pk_mul(f2 a, f2 b) {
  f2 d;
  asm("v_pk_mul_f32 %0, %1, %2" : "=v"(d) : "v"(a), "v"(b));
  return d;
}
__device__ __forceinline__ f2 pk_fma(f2 a, f2 b, f2 c) {
  f2 d;
  asm("v_pk_fma_f32 %0, %1, %2, %3" : "=v"(d) : "v"(a), "v"(b), "v"(c));
  return d;
}
__device__ __forceinline__ f2 pk_add(f2 a, f2 b) {
  f2 d;
  asm("v_pk_add_f32 %0, %1, %2" : "=v"(d) : "v"(a), "v"(b));
  return d;
}

// DPP move helper: ctrl must be compile-time constant.
template <int CTRL>
__device__ __forceinline__ float dpp_mov_f32(float x) {
  int r = __builtin_amdgcn_update_dpp(0, __float_as_int(x), CTRL, 0xF, 0xF, true);
  return __int_as_float(r);
}

// Full sum across a 16-lane DPP row via rotations (all lanes end with total).
__device__ __forceinline__ float row16_sum(float s) {
  s += dpp_mov_f32<0x128>(s);  // row_ror:8
  s += dpp_mov_f32<0x124>(s);  // row_ror:4
  s += dpp_mov_f32<0x122>(s);  // row_ror:2
  s += dpp_mov_f32<0x121>(s);  // row_ror:1
  return s;
}

// Sum a packed pair across the 4 16-lane rows of a wave (lane^16, lane^32).
__device__ __forceinline__ f2 dq4_sum2(f2 x) {
#if defined(__has_builtin)
#if __has_builtin(__builtin_amdgcn_permlane16_swap) && __has_builtin(__builtin_amdgcn_permlane32_swap)
  {
    typedef unsigned u2 __attribute__((ext_vector_type(2)));
    u2 ra = __builtin_amdgcn_permlane16_swap(__float_as_uint(x.x), __float_as_uint(x.x), false, false);
    u2 rb = __builtin_amdgcn_permlane16_swap(__float_as_uint(x.y), __float_as_uint(x.y), false, false);
    f2 lo = {__uint_as_float(ra.x), __uint_as_float(rb.x)};
    f2 hi = {__uint_as_float(ra.y), __uint_as_float(rb.y)};
    x = pk_add(lo, hi);
    ra = __builtin_amdgcn_permlane32_swap(__float_as_uint(x.x), __float_as_uint(x.x), false, false);
    rb = __builtin_amdgcn_permlane32_swap(__float_as_uint(x.y), __float_as_uint(x.y), false, false);
    lo = (f2){__uint_as_float(ra.x), __uint_as_float(rb.x)};
    hi = (f2){__uint_as_float(ra.y), __uint_as_float(rb.y)};
    return pk_add(lo, hi);
  }
#else
  x.x += __shfl_xor(x.x, 16); x.y += __shfl_xor(x.y, 16);
  x.x += __shfl_xor(x.x, 32); x.y += __shfl_xor(x.y, 32);
  return x;
#endif
#else
  x.x += __shfl_xor(x.x, 16); x.y += __shfl_xor(x.y, 16);
  x.x += __shfl_xor(x.x, 32); x.y += __shfl_xor(x.y, 32);
  return x;
#endif
}

// One block (1024 threads = 16 waves) per matrix. Thread (tx=tid&15, ty=tid>>4)
// owns rows [4*ty,4*ty+4), cols [16*tx,16*tx+16). V0 = exp(alpha/tau) is held
// as PACKED BF16 pairs (32 VGPRs) so total live state (~96 regs) fits the
// 128-reg budget at 4 waves/EU -- small enough that the allocator has no
// reason to shunt it to AGPRs (the R4-R6 copy tax). Unpack is 2 VALU/pair.
// Scales stay f32: R_i = 1/sum_j V0[ij]*C_j ; C_j = 1/sum_i V0[ij]*R_i, fused
// so each V0 element is unpacked once per iteration.
__global__ __launch_bounds__(1024)
__attribute__((amdgpu_waves_per_eu(4, 4)))
void sinkhorn16(const float* __restrict__ alpha, float* __restrict__ out) {
  // k-major partial layout: partial for col 16*x+4*k+m of wave w lives at
  // colpart[w*256 + k*64 + x*4 + m]  -> all LDS phases conflict-free
  // (verified: SQ_LDS_BANK_CONFLICT == 0 in R2/R4/R5/R6 with this layout).
  __shared__ float colpart[16 * 256];
  __shared__ float colrcp[256];

  const int tid = threadIdx.x;
  const int tx  = tid & 15;
  const int ty  = tid >> 4;         // 0..63
  const int dq  = (tid >> 4) & 3;   // lane>>4
  const int wv  = tid >> 6;         // 0..15

  const size_t mbase = (size_t)blockIdx.x * (256 * 256);
  const float* A = alpha + mbase;
  float*       O = out + mbase;

  unsigned vp[4][8];  // packed bf16 pairs: row i, col pair c = cols {2c,2c+1}

  // Load + exp(alpha/TAU) (1/0.1f is exactly 10.0f), RNE-round to bf16, pack.
#pragma unroll
  for (int i = 0; i < 4; ++i) {
    const float4* src = (const float4*)(A + (size_t)(4 * ty + i) * 256 + 16 * tx);
#pragma unroll
    for (int k = 0; k < 4; ++k) {
      float4 x = src[k];
      unsigned u0 = __float_as_uint(__expf(x.x * 10.0f));
      unsigned u1 = __float_as_uint(__expf(x.y * 10.0f));
      unsigned u2 = __float_as_uint(__expf(x.z * 10.0f));
      unsigned u3 = __float_as_uint(__expf(x.w * 10.0f));
      u0 = (u0 + 0x7FFFu + ((u0 >> 16) & 1u)) >> 16;  // round-to-nearest-even
      u1 = (u1 + 0x7FFFu + ((u1 >> 16) & 1u)) >> 16;
      u2 = (u2 + 0x7FFFu + ((u2 >> 16) & 1u)) >> 16;
      u3 = (u3 + 0x7FFFu + ((u3 >> 16) & 1u)) >> 16;
      vp[i][2 * k + 0] = u0 | (u1 << 16);
      vp[i][2 * k + 1] = u2 | (u3 << 16);
    }
  }

  f2 C[8];
  float R[4];
#pragma unroll
  for (int j = 0; j < 8; ++j) C[j] = (f2){1.0f, 1.0f};

  for (int it = 0; it < N_ITER; ++it) {
    // ---- fused row+col phase: unpack row once, use for R_i and p_j ----
    f2 p[8];
#pragma unroll
    for (int i = 0; i < 4; ++i) {
      f2 w[8];  // unpacked row i (bf16 -> f32 is a 16-bit shift)
#pragma unroll
      for (int c = 0; c < 8; ++c) {
        unsigned pk = vp[i][c];
        w[c].x = __uint_as_float(pk << 16);
        w[c].y = __uint_as_float(pk & 0xFFFF0000u);
      }
      f2 a0 = pk_mul(w[0], C[0]);
      f2 a1 = pk_mul(w[1], C[1]);
#pragma unroll
      for (int m = 1; m < 4; ++m) {
        a0 = pk_fma(w[2 * m + 0], C[2 * m + 0], a0);
        a1 = pk_fma(w[2 * m + 1], C[2 * m + 1], a1);
      }
      f2 a = pk_add(a0, a1);
      float s = row16_sum(a.x + a.y);  // sum over the 16 tx threads
      float Ri = __builtin_amdgcn_rcpf(s);
      R[i] = Ri;
      const f2 RRi = (f2){Ri, Ri};
      if (i == 0) {
#pragma unroll
        for (int j = 0; j < 8; ++j) p[j] = pk_mul(w[j], RRi);
      } else {
#pragma unroll
        for (int j = 0; j < 8; ++j) p[j] = pk_fma(w[j], RRi, p[j]);
      }
    }

    // sum p over the wave's 4 row-groups (16 rows)
#pragma unroll
    for (int j = 0; j < 8; ++j) p[j] = dq4_sum2(p[j]);

    if (dq == 0) {  // 16 lanes per wave write the wave's 256 col partials
      float* dst = &colpart[wv * 256 + tx * 4];
#pragma unroll
      for (int k = 0; k < 4; ++k)
        *((float4*)(dst + k * 64)) =
            make_float4(p[2 * k].x, p[2 * k].y, p[2 * k + 1].x, p[2 * k + 1].y);
    }
    __syncthreads();

    if (tid < 256) {  // sum 16 wave-partials per col, reciprocal (conflict-free)
      float c0 = colpart[0 * 256 + tid] + colpart[1 * 256 + tid];
      float c1 = colpart[2 * 256 + tid] + colpart[3 * 256 + tid];
      float c2 = colpart[4 * 256 + tid] + colpart[5 * 256 + tid];
      float c3 = colpart[6 * 256 + tid] + colpart[7 * 256 + tid];
      float c4 = colpart[8 * 256 + tid] + colpart[9 * 256 + tid];
      float c5 = colpart[10 * 256 + tid] + colpart[11 * 256 + tid];
      float c6 = colpart[12 * 256 + tid] + colpart[13 * 256 + tid];
      float c7 = colpart[14 * 256 + tid] + colpart[15 * 256 + tid];
      float s = ((c0 + c1) + (c2 + c3)) + ((c4 + c5) + (c6 + c7));
      colrcp[tid] = __builtin_amdgcn_rcpf(s);
    }
    __syncthreads();

    // broadcast new C (k-major: conflict-free)
#pragma unroll
    for (int k = 0; k < 4; ++k) {
      float4 rc = *((const float4*)(&colrcp[k * 64 + tx * 4]));
      C[2 * k + 0] = (f2){rc.x, rc.y};
      C[2 * k + 1] = (f2){rc.z, rc.w};
    }
  }

  // ---------- epilogue: out = V0 * R_i * C_j ----------
#pragma unroll
  for (int i = 0; i < 4; ++i) {
    const f2 Ri = (f2){R[i], R[i]};
    float4* dst = (float4*)(O + (size_t)(4 * ty + i) * 256 + 16 * tx);
#pragma unroll
    for (int k = 0; k < 4; ++k) {
      unsigned p0 = vp[i][2 * k + 0];
      unsigned p1 = vp[i][2 * k + 1];
      f2 lo = {__uint_as_float(p0 << 16), __uint_as_float(p0 & 0xFFFF0000u)};
      f2 hi = {__uint_as_float(p1 << 16), __uint_as_float(p1 & 0xFFFF0000u)};
      lo = pk_mul(pk_mul(lo, Ri), C[2 * k + 0]);
      hi = pk_mul(pk_mul(hi, Ri), C[2 * k + 1]);
      dst[k] = make_float4(lo.x, lo.y, hi.x, hi.y);
    }
  }
}

extern "C" void kernel_launch(void* const* d_in, const int* in_sizes, int n_in,
                              void* d_out, int out_size, void* d_ws, size_t ws_size,
                              hipStream_t stream) {
  const float* alpha = (const float*)d_in[0];
  float* out = (float*)d_out;
  sinkhorn16<<<dim3(16), dim3(1024), 0, stream>>>(alpha, out);
}

// Round 8
// 200.913 us; speedup vs baseline: 1.2345x; 1.2345x over previous
//
#include <hip/hip_runtime.h>

#define N_ITER 100

typedef short s16x8 __attribute__((ext_vector_type(8)));
typedef float f32x4 __attribute__((ext_vector_type(4)));
typedef unsigned u32x4 __attribute__((ext_vector_type(4)));

// RNE-pack two f32 into a dword of two bf16 (proven in R7: absmax 3.9e-3).
__device__ __forceinline__ unsigned bf16pack(float a, float b) {
  unsigned ua = __float_as_uint(a), ub = __float_as_uint(b);
  ua = (ua + 0x7FFFu + ((ua >> 16) & 1u)) >> 16;
  ub = (ub + 0x7FFFu + ((ub >> 16) & 1u)) >> 16;
  return ua | (ub << 16);
}

// One block (1024 threads = 16 waves) per matrix. Wave w owns rows
// [16w,16w+16) of V0 (arow frags) and cols [16w,16w+16) of V0 (acol frags =
// A-frags of V0^T). Scales are broadcast through the MFMA B operand: every
// lane loads the same 16B of bf16 scales per K-chunk, so B[k][n] = scale[32c+k]
// for all n and every column of D holds the same correct sum -- no masking.
// Layouts (guide §3, m89/m120 verified): A elem j <-> A[m=lane&15][k=8q+j];
// D reg r <-> row 4q+r (col = lane&15, all cols equal here).
__global__ __launch_bounds__(1024) void sinkhorn_mfma(const float* __restrict__ alpha,
                                                      float* __restrict__ out) {
  __shared__ alignas(16) unsigned short Cb16[256];
  __shared__ alignas(16) unsigned short Rb16[256];
  __shared__ alignas(16) float Cb32[256];
  __shared__ alignas(16) float Rb32[256];

  const int tid  = threadIdx.x;
  const int lane = tid & 63;
  const int w    = tid >> 6;   // wave 0..15
  const int m    = lane & 15;
  const int q    = lane >> 4;

  const size_t mbase = (size_t)blockIdx.x * (256 * 256);
  const float* A = alpha + mbase;
  float*       O = out + mbase;

  // arow[c] elem j <-> V0[16w+m][32c+8q+j]; acol[c] elem j <-> V0[32c+8q+j][16w+m]
  unsigned arow[8][4];
  unsigned acol[8][4];

  {
    const float* rowp = A + (size_t)(16 * w + m) * 256 + 8 * q;
#pragma unroll
    for (int c = 0; c < 8; ++c) {
      const float4* s4 = (const float4*)(rowp + 32 * c);  // 32B-aligned
      float4 x0 = s4[0], x1 = s4[1];
      arow[c][0] = bf16pack(__expf(x0.x * 10.0f), __expf(x0.y * 10.0f));
      arow[c][1] = bf16pack(__expf(x0.z * 10.0f), __expf(x0.w * 10.0f));
      arow[c][2] = bf16pack(__expf(x1.x * 10.0f), __expf(x1.y * 10.0f));
      arow[c][3] = bf16pack(__expf(x1.z * 10.0f), __expf(x1.w * 10.0f));
    }
    const float* colp = A + (size_t)(8 * q) * 256 + 16 * w + m;
#pragma unroll
    for (int c = 0; c < 8; ++c) {
      const float* p = colp + (size_t)(32 * c) * 256;
#pragma unroll
      for (int r = 0; r < 4; ++r) {
        float e0 = __expf(p[(2 * r) * 256] * 10.0f);
        float e1 = __expf(p[(2 * r + 1) * 256] * 10.0f);
        acol[c][r] = bf16pack(e0, e1);
      }
    }
  }

  if (tid < 256) { Cb16[tid] = 0x3F80; Cb32[tid] = 1.0f; }  // C = 1
  __syncthreads();

  for (int it = 0; it < N_ITER; ++it) {
    // ---------- phase 1: s = V0_rowslab · C ; R = 1/s ----------
    f32x4 acc0 = {0.f, 0.f, 0.f, 0.f}, acc1 = {0.f, 0.f, 0.f, 0.f};
#pragma unroll
    for (int c = 0; c < 8; c += 2) {
      s16x8 b0 = __builtin_bit_cast(s16x8, *(const u32x4*)&Cb16[32 * c + 8 * q]);
      s16x8 a0 = __builtin_bit_cast(s16x8, *(const u32x4*)arow[c]);
      acc0 = __builtin_amdgcn_mfma_f32_16x16x32_bf16(a0, b0, acc0, 0, 0, 0);
      s16x8 b1 = __builtin_bit_cast(s16x8, *(const u32x4*)&Cb16[32 * (c + 1) + 8 * q]);
      s16x8 a1 = __builtin_bit_cast(s16x8, *(const u32x4*)arow[c + 1]);
      acc1 = __builtin_amdgcn_mfma_f32_16x16x32_bf16(a1, b1, acc1, 0, 0, 0);
    }
    {
      f32x4 s = acc0 + acc1;  // reg r = rowsum of row 16w+4q+r (all lanes)
      if (m == 0) {           // one writer per (w,q): rows 16w+4q..+3
        float r0 = __builtin_amdgcn_rcpf(s[0]);
        float r1 = __builtin_amdgcn_rcpf(s[1]);
        float r2 = __builtin_amdgcn_rcpf(s[2]);
        float r3 = __builtin_amdgcn_rcpf(s[3]);
        *(float4*)&Rb32[16 * w + 4 * q] = make_float4(r0, r1, r2, r3);
        *(uint2*)&Rb16[16 * w + 4 * q] = make_uint2(bf16pack(r0, r1), bf16pack(r2, r3));
      }
    }
    __syncthreads();

    // ---------- phase 2: t = V0^T_colslab · R ; C = 1/t ----------
    f32x4 bcc0 = {0.f, 0.f, 0.f, 0.f}, bcc1 = {0.f, 0.f, 0.f, 0.f};
#pragma unroll
    for (int c = 0; c < 8; c += 2) {
      s16x8 b0 = __builtin_bit_cast(s16x8, *(const u32x4*)&Rb16[32 * c + 8 * q]);
      s16x8 a0 = __builtin_bit_cast(s16x8, *(const u32x4*)acol[c]);
      bcc0 = __builtin_amdgcn_mfma_f32_16x16x32_bf16(a0, b0, bcc0, 0, 0, 0);
      s16x8 b1 = __builtin_bit_cast(s16x8, *(const u32x4*)&Rb16[32 * (c + 1) + 8 * q]);
      s16x8 a1 = __builtin_bit_cast(s16x8, *(const u32x4*)acol[c + 1]);
      bcc1 = __builtin_amdgcn_mfma_f32_16x16x32_bf16(a1, b1, bcc1, 0, 0, 0);
    }
    {
      f32x4 t = bcc0 + bcc1;  // reg r = colsum of col 16w+4q+r (all lanes)
      if (m == 0) {
        float c0 = __builtin_amdgcn_rcpf(t[0]);
        float c1 = __builtin_amdgcn_rcpf(t[1]);
        float c2 = __builtin_amdgcn_rcpf(t[2]);
        float c3 = __builtin_amdgcn_rcpf(t[3]);
        *(float4*)&Cb32[16 * w + 4 * q] = make_float4(c0, c1, c2, c3);
        *(uint2*)&Cb16[16 * w + 4 * q] = make_uint2(bf16pack(c0, c1), bf16pack(c2, c3));
      }
    }
    __syncthreads();
  }

  // ---------- epilogue: out = diag(R32) · V0_bf16 · diag(C32) ----------
  const float Rm = Rb32[16 * w + m];
#pragma unroll
  for (int c = 0; c < 8; ++c) {
    float4 c0 = *(const float4*)&Cb32[32 * c + 8 * q];
    float4 c1 = *(const float4*)&Cb32[32 * c + 8 * q + 4];
    unsigned p0 = arow[c][0], p1 = arow[c][1], p2 = arow[c][2], p3 = arow[c][3];
    float4 o0, o1;
    o0.x = __uint_as_float(p0 << 16) * Rm * c0.x;
    o0.y = __uint_as_float(p0 & 0xFFFF0000u) * Rm * c0.y;
    o0.z = __uint_as_float(p1 << 16) * Rm * c0.z;
    o0.w = __uint_as_float(p1 & 0xFFFF0000u) * Rm * c0.w;
    o1.x = __uint_as_float(p2 << 16) * Rm * c1.x;
    o1.y = __uint_as_float(p2 & 0xFFFF0000u) * Rm * c1.y;
    o1.z = __uint_as_float(p3 << 16) * Rm * c1.z;
    o1.w = __uint_as_float(p3 & 0xFFFF0000u) * Rm * c1.w;
    float* dst = O + (size_t)(16 * w + m) * 256 + 32 * c + 8 * q;
    *(float4*)dst = o0;
    *(float4*)(dst + 4) = o1;
  }
}

extern "C" void kernel_launch(void* const* d_in, const int* in_sizes, int n_in,
                              void* d_out, int out_size, void* d_ws, size_t ws_size,
                              hipStream_t stream) {
  const float* alpha = (const float*)d_in[0];
  float* out = (float*)d_out;
  sinkhorn_mfma<<<dim3(16), dim3(1024), 0, stream>>>(alpha, out);
}